// Round 1
// baseline (358.351 us; speedup 1.0000x reference)
//
#include <hip/hip_runtime.h>
#include <cstdint>
#include <cstddef>

typedef unsigned short u16;
typedef __bf16 bf16x8 __attribute__((ext_vector_type(8)));
typedef u16 u16x8 __attribute__((ext_vector_type(8)));
typedef float f32x4 __attribute__((ext_vector_type(4)));

#define N_NODES 100000
#define SAMPLE 25
#define FEAT 128
#define CLASSES 40

__device__ __forceinline__ float bf2f(u16 v) {
    return __uint_as_float(((unsigned)v) << 16);
}
__device__ __forceinline__ u16 f2bf(float f) {
    unsigned u = __float_as_uint(f);
    u += 0x7FFFu + ((u >> 16) & 1u);
    return (u16)(u >> 16);
}
__device__ __forceinline__ void split_bf(float x, u16& hi, u16& lo) {
    hi = f2bf(x);
    lo = f2bf(x - bf2f(hi));
}

__device__ __forceinline__ void split8(const float* ap, bf16x8& ah, bf16x8& al) {
    union { u16x8 u; bf16x8 b; } H, L;
    #pragma unroll
    for (int j = 0; j < 8; ++j) {
        u16 h, lo; split_bf(ap[j], h, lo);
        H.u[j] = h; L.u[j] = lo;
    }
    ah = H.b; al = L.b;
}

__device__ __forceinline__ f32x4 mfma_split(bf16x8 ah, bf16x8 al,
                                            bf16x8 bh, bf16x8 bl, f32x4 acc) {
    acc = __builtin_amdgcn_mfma_f32_16x16x32_bf16(ah, bh, acc, 0, 0, 0);
    acc = __builtin_amdgcn_mfma_f32_16x16x32_bf16(al, bh, acc, 0, 0, 0);
    acc = __builtin_amdgcn_mfma_f32_16x16x32_bf16(ah, bl, acc, 0, 0, 0);
    return acc;
}

// async 16B global -> LDS (fire-and-forget; tracked by vmcnt).
// LDS dest is wave-uniform base; HW lands lane i at base + i*16.
__device__ __forceinline__ void gload_lds16(const void* g, void* l) {
    __builtin_amdgcn_global_load_lds(
        (const __attribute__((address_space(1))) unsigned int*)g,
        (__attribute__((address_space(3))) unsigned int*)l,
        16, 0, 0);
}

// ---------------------------------------------------------------------------
// Prep: split fp32 weights into bf16 hi/lo pairs
// ---------------------------------------------------------------------------
__global__ __launch_bounds__(256) void prep_weights(
    const float* __restrict__ W1, const float* __restrict__ W2,
    const float* __restrict__ Wl,
    u16* __restrict__ w1h, u16* __restrict__ w1l,
    u16* __restrict__ w2h, u16* __restrict__ w2l,
    u16* __restrict__ wlh, u16* __restrict__ wll)
{
    const int i = blockIdx.x * 256 + threadIdx.x;
    const int stride = gridDim.x * 256;
    for (int j = i; j < FEAT * FEAT; j += stride) {
        split_bf(W1[j], w1h[j], w1l[j]);
        split_bf(W2[j], w2h[j], w2l[j]);
    }
    for (int j = i; j < CLASSES * FEAT; j += stride) {
        split_bf(Wl[j], wlh[j], wll[j]);
    }
}

// ===========================================================================
// FAST PATH: commuted scheme (Z1 = X@W1^T first, then gather bf16 rows)
// ===========================================================================
#define NPB32 32

// K1: Z1 = X @ W1^T  (dense streamed GEMM, bf16 out, LDS-staged stores)
__global__ __launch_bounds__(128, 4) void k1_gemm(
    const float* __restrict__ X,
    const u16* __restrict__ w1h, const u16* __restrict__ w1l,
    u16* __restrict__ Z1)
{
    __shared__ u16 zt[NPB32][136];   // 8.7 KB

    const int t = threadIdx.x;
    const int w  = t >> 6;
    const int l  = t & 63;
    const int lr = l & 15;
    const int lq = l >> 4;
    const int blockStart = blockIdx.x * NPB32;
    const float* Xrow = X + (size_t)(blockStart + w * 16 + lr) * FEAT;

    bf16x8 ah[4], al[4];
    #pragma unroll
    for (int k = 0; k < 4; ++k) {
        f32x4 x0 = *(const f32x4*)(Xrow + k * 32 + lq * 8);
        f32x4 x1 = *(const f32x4*)(Xrow + k * 32 + lq * 8 + 4);
        float tmp[8];
        #pragma unroll
        for (int j = 0; j < 4; ++j) { tmp[j] = x0[j]; tmp[4 + j] = x1[j]; }
        split8(tmp, ah[k], al[k]);
    }

    #pragma unroll
    for (int c = 0; c < 8; ++c) {
        f32x4 acc = {0.f, 0.f, 0.f, 0.f};
        #pragma unroll
        for (int k = 0; k < 4; ++k) {
            const size_t off = (size_t)(c * 16 + lr) * FEAT + k * 32 + lq * 8;
            bf16x8 bh = *(const bf16x8*)(w1h + off);
            bf16x8 bl = *(const bf16x8*)(w1l + off);
            acc = mfma_split(ah[k], al[k], bh, bl, acc);
        }
        #pragma unroll
        for (int r = 0; r < 4; ++r)
            zt[w * 16 + lq * 4 + r][c * 16 + lr] = f2bf(acc[r]);  // no relu
    }
    __syncthreads();

    #pragma unroll
    for (int p = 0; p < 4; ++p) {
        const int idx = p * 128 + t;
        const int row = idx >> 4;
        const int col = (idx & 15) * 8;
        *(u16x8*)(Z1 + (size_t)(blockStart + row) * FEAT + col) =
            *(const u16x8*)&zt[row][col];
    }
}

// ---------------------------------------------------------------------------
// Pipelined gather (shared by k2/k3):
//   per wave: 16 nodes; slot = one sample's 16 neighbor rows staged via
//   4x global_load_lds (4 rows = 1 KB each), double-buffered.
//   Group stride 1056 B (pad 32) -> readback ds_read_b128 bank-quad index
//   = (2*(r>>2) + lq + 4k) mod 8: perfect 8-lane/quad tiling (BW floor).
//   Each lane accumulates its MFMA A-fragment directly: node lr,
//   features k*32 + lq*8  -> no agg-LDS relayout at all.
// ---------------------------------------------------------------------------
#define SLOT_BYTES   4224   // 4 groups * 1056
#define GROUP_STRIDE 1056   // 1024 + 32 pad
#define WAVE_BYTES   8448   // 2 slots

// K2: h1 = relu(mean(Z1[nb])); Z2 = h1 @ W2^T (bf16, LDS-staged stores)
__global__ __launch_bounds__(128, 4) void k2_hop(
    const u16* __restrict__ Zin, const int* __restrict__ nb,
    const u16* __restrict__ wh, const u16* __restrict__ wl,
    u16* __restrict__ Zout)
{
    __shared__ __align__(16) char slots[2 * WAVE_BYTES];  // 16896 B, zt alias
    __shared__ int nbs[NPB32 * SAMPLE];                   // 3200 B

    const int t = threadIdx.x;
    const int w  = t >> 6;
    const int l  = t & 63;
    const int lr = l & 15;
    const int lq = l >> 4;
    const int blockStart = blockIdx.x * NPB32;

    for (int i = t; i < NPB32 * SAMPLE; i += 128)
        nbs[i] = nb[blockStart * SAMPLE + i];
    __syncthreads();

    char* base = slots + w * WAVE_BYTES;
    // staging lane mapping: lane i -> row (i>>4) of group, chunk (i&15)
    const int srow = lq;      // l>>4: row within 4-row group
    const int schk = lr;      // l&15: 16B chunk within row
    // readback base for this lane's node (row lr of the wave's 16)
    char* rb0 = base + (lr >> 2) * GROUP_STRIDE + (lr & 3) * 256;

    #define STAGE(s, slot)                                                    \
        {                                                                     \
            _Pragma("unroll")                                                 \
            for (int g = 0; g < 4; ++g) {                                     \
                const int nbrow = nbs[(w * 16 + g * 4 + srow) * SAMPLE + (s)];\
                const u16* src = Zin + ((size_t)nbrow << 7) + schk * 8;       \
                gload_lds16(src, base + (slot) * SLOT_BYTES + g * GROUP_STRIDE);\
            }                                                                 \
        }

    float acc[4][8];
    #pragma unroll
    for (int k = 0; k < 4; ++k)
        #pragma unroll
        for (int j = 0; j < 8; ++j) acc[k][j] = 0.f;

    #define CONSUME(slot)                                                     \
        {                                                                     \
            const char* rb = rb0 + (slot) * SLOT_BYTES;                       \
            _Pragma("unroll")                                                 \
            for (int k = 0; k < 4; ++k) {                                     \
                u16x8 v = *(const u16x8*)(rb + (4 * k + lq) * 16);            \
                _Pragma("unroll")                                             \
                for (int j = 0; j < 8; ++j) acc[k][j] += bf2f(v[j]);          \
            }                                                                 \
        }

    STAGE(0, 0);
    STAGE(1, 1);
    #pragma unroll 1
    for (int s = 0; s < SAMPLE - 2; ++s) {
        asm volatile("s_waitcnt vmcnt(4)" ::: "memory");  // sample s landed
        CONSUME(s & 1);
        // ds_read data must be in regs before DMA may overwrite the slot
        asm volatile("s_waitcnt lgkmcnt(0)" ::: "memory");
        __builtin_amdgcn_sched_barrier(0);
        STAGE(s + 2, s & 1);
    }
    asm volatile("s_waitcnt vmcnt(4)" ::: "memory");
    CONSUME(1);                                           // sample 23
    asm volatile("s_waitcnt vmcnt(0)" ::: "memory");
    CONSUME(0);                                           // sample 24

    // mean + relu + split into A-fragments (registers only)
    bf16x8 ah[4], al[4];
    #pragma unroll
    for (int k = 0; k < 4; ++k) {
        float tmp[8];
        #pragma unroll
        for (int j = 0; j < 8; ++j) {
            float m = acc[k][j] * (1.0f / SAMPLE);
            tmp[j] = m > 0.f ? m : 0.f;
        }
        split8(tmp, ah[k], al[k]);
    }
    __syncthreads();                      // all waves done with slots

    u16* zt = (u16*)slots;                // [NPB32][136] alias

    #pragma unroll
    for (int c = 0; c < 8; ++c) {
        f32x4 o = {0.f, 0.f, 0.f, 0.f};
        #pragma unroll
        for (int k = 0; k < 4; ++k) {
            const size_t off = (size_t)(c * 16 + lr) * FEAT + k * 32 + lq * 8;
            bf16x8 bh = *(const bf16x8*)(wh + off);
            bf16x8 bl = *(const bf16x8*)(wl + off);
            o = mfma_split(ah[k], al[k], bh, bl, o);
        }
        #pragma unroll
        for (int r = 0; r < 4; ++r)
            zt[(size_t)(w * 16 + lq * 4 + r) * 136 + c * 16 + lr] = f2bf(o[r]);
    }
    __syncthreads();

    #pragma unroll
    for (int p = 0; p < 4; ++p) {
        const int idx = p * 128 + t;
        const int row = idx >> 4;
        const int col = (idx & 15) * 8;
        *(u16x8*)(Zout + (size_t)(blockStart + row) * FEAT + col) =
            *(const u16x8*)&zt[(size_t)row * 136 + col];
    }
    #undef STAGE
    #undef CONSUME
}

// K3: h2 = relu(mean(Z2[nb])); out = h2 @ Wlast^T (fp32, direct stores)
__global__ __launch_bounds__(128, 4) void k3_hop(
    const u16* __restrict__ Zin, const int* __restrict__ nb,
    const u16* __restrict__ wh, const u16* __restrict__ wl,
    float* __restrict__ out)
{
    __shared__ __align__(16) char slots[2 * WAVE_BYTES];
    __shared__ int nbs[NPB32 * SAMPLE];

    const int t = threadIdx.x;
    const int w  = t >> 6;
    const int l  = t & 63;
    const int lr = l & 15;
    const int lq = l >> 4;
    const int blockStart = blockIdx.x * NPB32;

    for (int i = t; i < NPB32 * SAMPLE; i += 128)
        nbs[i] = nb[blockStart * SAMPLE + i];
    __syncthreads();

    char* base = slots + w * WAVE_BYTES;
    const int srow = lq;
    const int schk = lr;
    char* rb0 = base + (lr >> 2) * GROUP_STRIDE + (lr & 3) * 256;

    #define STAGE(s, slot)                                                    \
        {                                                                     \
            _Pragma("unroll")                                                 \
            for (int g = 0; g < 4; ++g) {                                     \
                const int nbrow = nbs[(w * 16 + g * 4 + srow) * SAMPLE + (s)];\
                const u16* src = Zin + ((size_t)nbrow << 7) + schk * 8;       \
                gload_lds16(src, base + (slot) * SLOT_BYTES + g * GROUP_STRIDE);\
            }                                                                 \
        }

    float acc[4][8];
    #pragma unroll
    for (int k = 0; k < 4; ++k)
        #pragma unroll
        for (int j = 0; j < 8; ++j) acc[k][j] = 0.f;

    #define CONSUME(slot)                                                     \
        {                                                                     \
            const char* rb = rb0 + (slot) * SLOT_BYTES;                       \
            _Pragma("unroll")                                                 \
            for (int k = 0; k < 4; ++k) {                                     \
                u16x8 v = *(const u16x8*)(rb + (4 * k + lq) * 16);            \
                _Pragma("unroll")                                             \
                for (int j = 0; j < 8; ++j) acc[k][j] += bf2f(v[j]);          \
            }                                                                 \
        }

    STAGE(0, 0);
    STAGE(1, 1);
    #pragma unroll 1
    for (int s = 0; s < SAMPLE - 2; ++s) {
        asm volatile("s_waitcnt vmcnt(4)" ::: "memory");
        CONSUME(s & 1);
        asm volatile("s_waitcnt lgkmcnt(0)" ::: "memory");
        __builtin_amdgcn_sched_barrier(0);
        STAGE(s + 2, s & 1);
    }
    asm volatile("s_waitcnt vmcnt(4)" ::: "memory");
    CONSUME(1);
    asm volatile("s_waitcnt vmcnt(0)" ::: "memory");
    CONSUME(0);

    bf16x8 ah[4], al[4];
    #pragma unroll
    for (int k = 0; k < 4; ++k) {
        float tmp[8];
        #pragma unroll
        for (int j = 0; j < 8; ++j) {
            float m = acc[k][j] * (1.0f / SAMPLE);
            tmp[j] = m > 0.f ? m : 0.f;
        }
        split8(tmp, ah[k], al[k]);
    }

    #pragma unroll
    for (int c = 0; c < 3; ++c) {
        const int o = c * 16 + lr;
        f32x4 acc2 = {0.f, 0.f, 0.f, 0.f};
        #pragma unroll
        for (int k = 0; k < 4; ++k) {
            bf16x8 bh, bl;
            if (o < CLASSES) {
                const size_t off = (size_t)o * FEAT + k * 32 + lq * 8;
                bh = *(const bf16x8*)(wh + off);
                bl = *(const bf16x8*)(wl + off);
            } else {
                #pragma unroll
                for (int j = 0; j < 8; ++j) { bh[j] = (__bf16)0.f; bl[j] = (__bf16)0.f; }
            }
            acc2 = mfma_split(ah[k], al[k], bh, bl, acc2);
        }
        if (o < CLASSES) {
            #pragma unroll
            for (int r = 0; r < 4; ++r) {
                const int node = blockStart + w * 16 + lq * 4 + r;
                out[(size_t)node * CLASSES + o] = acc2[r];
            }
        }
    }
    #undef STAGE
    #undef CONSUME
}

// ===========================================================================
// FALLBACK PATH (proven R2 kernels, ws >= 25.9 MB only)
// ===========================================================================
#define NPB 64
#define AGG_STRIDE 136

__global__ __launch_bounds__(256) void gnn_layer1(
    const float* __restrict__ X, const int* __restrict__ nb,
    const u16* __restrict__ w1h, const u16* __restrict__ w1l,
    u16* __restrict__ h1)
{
    __shared__ int nbs[NPB * SAMPLE];
    __shared__ u16 agg_h[NPB][AGG_STRIDE];
    __shared__ u16 agg_l[NPB][AGG_STRIDE];

    const int t = threadIdx.x;
    const int blockStart = blockIdx.x * NPB;

    for (int i = t; i < NPB * SAMPLE; i += 256) {
        int gi = blockStart * SAMPLE + i;
        if (gi >= N_NODES * SAMPLE) gi = N_NODES * SAMPLE - 1;
        nbs[i] = nb[gi];
    }
    __syncthreads();

    for (int item = t; item < NPB * 16; item += 256) {
        const int nl = item >> 4;
        const int fg = item & 15;
        float acc[8];
        #pragma unroll
        for (int j = 0; j < 8; ++j) acc[j] = 0.f;
        const int* myn = &nbs[nl * SAMPLE];
        for (int s = 0; s < SAMPLE; ++s) {
            const float4* p = (const float4*)(X + (size_t)myn[s] * FEAT + fg * 8);
            float4 a = p[0], b = p[1];
            acc[0] += a.x; acc[1] += a.y; acc[2] += a.z; acc[3] += a.w;
            acc[4] += b.x; acc[5] += b.y; acc[6] += b.z; acc[7] += b.w;
        }
        u16x8 oh, ol;
        #pragma unroll
        for (int j = 0; j < 8; ++j) {
            float m = acc[j] * (1.0f / SAMPLE);
            u16 h, lo; split_bf(m, h, lo);
            oh[j] = h; ol[j] = lo;
        }
        *(u16x8*)&agg_h[nl][fg * 8] = oh;
        *(u16x8*)&agg_l[nl][fg * 8] = ol;
    }
    __syncthreads();

    const int w  = t >> 6;
    const int l  = t & 63;
    const int lr = l & 15;
    const int lq = l >> 4;

    bf16x8 ah[4], al[4];
    #pragma unroll
    for (int k = 0; k < 4; ++k) {
        ah[k] = *(const bf16x8*)&agg_h[w * 16 + lr][k * 32 + lq * 8];
        al[k] = *(const bf16x8*)&agg_l[w * 16 + lr][k * 32 + lq * 8];
    }

    #pragma unroll
    for (int c = 0; c < 8; ++c) {
        f32x4 acc = {0.f, 0.f, 0.f, 0.f};
        #pragma unroll
        for (int k = 0; k < 4; ++k) {
            const size_t off = (size_t)(c * 16 + lr) * FEAT + k * 32 + lq * 8;
            bf16x8 bh = *(const bf16x8*)(w1h + off);
            bf16x8 bl = *(const bf16x8*)(w1l + off);
            acc = mfma_split(ah[k], al[k], bh, bl, acc);
        }
        #pragma unroll
        for (int r = 0; r < 4; ++r) {
            int node = blockStart + w * 16 + lq * 4 + r;
            if (node < N_NODES) {
                float v = acc[r] > 0.f ? acc[r] : 0.f;
                h1[(size_t)node * FEAT + c * 16 + lr] = f2bf(v);
            }
        }
    }
}

__global__ __launch_bounds__(256) void gnn_layer2_final(
    const u16* __restrict__ h1, const int* __restrict__ nb,
    const u16* __restrict__ w2h, const u16* __restrict__ w2l,
    const u16* __restrict__ wlh, const u16* __restrict__ wll,
    float* __restrict__ out)
{
    __shared__ int nbs[NPB * SAMPLE];
    __shared__ u16 agg_h[NPB][AGG_STRIDE];
    __shared__ u16 agg_l[NPB][AGG_STRIDE];

    const int t = threadIdx.x;
    const int blockStart = blockIdx.x * NPB;

    for (int i = t; i < NPB * SAMPLE; i += 256) {
        int gi = blockStart * SAMPLE + i;
        if (gi >= N_NODES * SAMPLE) gi = N_NODES * SAMPLE - 1;
        nbs[i] = nb[gi];
    }
    __syncthreads();

    for (int item = t; item < NPB * 16; item += 256) {
        const int nl = item >> 4;
        const int fg = item & 15;
        float acc[8];
        #pragma unroll
        for (int j = 0; j < 8; ++j) acc[j] = 0.f;
        const int* myn = &nbs[nl * SAMPLE];
        for (int s = 0; s < SAMPLE; ++s) {
            u16x8 v = *(const u16x8*)(h1 + (size_t)myn[s] * FEAT + fg * 8);
            #pragma unroll
            for (int j = 0; j < 8; ++j) acc[j] += bf2f(v[j]);
        }
        u16x8 oh, ol;
        #pragma unroll
        for (int j = 0; j < 8; ++j) {
            float m = acc[j] * (1.0f / SAMPLE);
            u16 h, lo; split_bf(m, h, lo);
            oh[j] = h; ol[j] = lo;
        }
        *(u16x8*)&agg_h[nl][fg * 8] = oh;
        *(u16x8*)&agg_l[nl][fg * 8] = ol;
    }
    __syncthreads();

    const int w  = t >> 6;
    const int l  = t & 63;
    const int lr = l & 15;
    const int lq = l >> 4;

    f32x4 hacc[8];
    {
        bf16x8 ah[4], al[4];
        #pragma unroll
        for (int k = 0; k < 4; ++k) {
            ah[k] = *(const bf16x8*)&agg_h[w * 16 + lr][k * 32 + lq * 8];
            al[k] = *(const bf16x8*)&agg_l[w * 16 + lr][k * 32 + lq * 8];
        }
        #pragma unroll
        for (int c = 0; c < 8; ++c) {
            f32x4 acc = {0.f, 0.f, 0.f, 0.f};
            #pragma unroll
            for (int k = 0; k < 4; ++k) {
                const size_t off = (size_t)(c * 16 + lr) * FEAT + k * 32 + lq * 8;
                bf16x8 bh = *(const bf16x8*)(w2h + off);
                bf16x8 bl = *(const bf16x8*)(w2l + off);
                acc = mfma_split(ah[k], al[k], bh, bl, acc);
            }
            hacc[c] = acc;
        }
    }
    __syncthreads();

    #pragma unroll
    for (int c = 0; c < 8; ++c) {
        #pragma unroll
        for (int r = 0; r < 4; ++r) {
            float v = hacc[c][r] > 0.f ? hacc[c][r] : 0.f;
            u16 h, l2; split_bf(v, h, l2);
            agg_h[w * 16 + lq * 4 + r][c * 16 + lr] = h;
            agg_l[w * 16 + lq * 4 + r][c * 16 + lr] = l2;
        }
    }
    __syncthreads();

    {
        bf16x8 ah[4], al[4];
        #pragma unroll
        for (int k = 0; k < 4; ++k) {
            ah[k] = *(const bf16x8*)&agg_h[w * 16 + lr][k * 32 + lq * 8];
            al[k] = *(const bf16x8*)&agg_l[w * 16 + lr][k * 32 + lq * 8];
        }
        #pragma unroll
        for (int c = 0; c < 3; ++c) {
            const int o = c * 16 + lr;
            f32x4 acc = {0.f, 0.f, 0.f, 0.f};
            #pragma unroll
            for (int k = 0; k < 4; ++k) {
                bf16x8 bh, bl;
                if (o < CLASSES) {
                    const size_t off = (size_t)o * FEAT + k * 32 + lq * 8;
                    bh = *(const bf16x8*)(wlh + off);
                    bl = *(const bf16x8*)(wll + off);
                } else {
                    #pragma unroll
                    for (int j = 0; j < 8; ++j) { bh[j] = (__bf16)0.f; bl[j] = (__bf16)0.f; }
                }
                acc = mfma_split(ah[k], al[k], bh, bl, acc);
            }
            if (o < CLASSES) {
                #pragma unroll
                for (int r = 0; r < 4; ++r) {
                    int node = blockStart + w * 16 + lq * 4 + r;
                    if (node < N_NODES) {
                        out[(size_t)node * CLASSES + o] = acc[r];
                    }
                }
            }
        }
    }
}

extern "C" void kernel_launch(void* const* d_in, const int* in_sizes, int n_in,
                              void* d_out, int out_size, void* d_ws, size_t ws_size,
                              hipStream_t stream) {
    const float* X  = (const float*)d_in[0];
    const int*   nb = (const int*)d_in[1];
    const float* W1 = (const float*)d_in[2];
    const float* W2 = (const float*)d_in[3];
    const float* Wl = (const float*)d_in[4];
    float* out = (float*)d_out;

    const size_t zelems = (size_t)N_NODES * FEAT;                 // 12.8M
    const size_t welems = 4 * (size_t)FEAT * FEAT + 2 * (size_t)CLASSES * FEAT;
    const size_t need_fast = (2 * zelems + welems) * sizeof(u16); // ~51.4 MB

    if (ws_size >= need_fast) {
        u16* Z1  = (u16*)d_ws;
        u16* Z2  = Z1 + zelems;
        u16* w1h = Z2 + zelems;
        u16* w1l = w1h + FEAT * FEAT;
        u16* w2h = w1l + FEAT * FEAT;
        u16* w2l = w2h + FEAT * FEAT;
        u16* wlh = w2l + FEAT * FEAT;
        u16* wll = wlh + CLASSES * FEAT;

        prep_weights<<<64, 256, 0, stream>>>(W1, W2, Wl, w1h, w1l, w2h, w2l, wlh, wll);
        const int blocks = N_NODES / NPB32;  // 3125, exact
        k1_gemm<<<blocks, 128, 0, stream>>>(X, w1h, w1l, Z1);
        k2_hop<<<blocks, 128, 0, stream>>>(Z1, nb, w2h, w2l, Z2);
        k3_hop<<<blocks, 128, 0, stream>>>(Z2, nb, wlh, wll, out);
    } else {
        u16* h1  = (u16*)d_ws;
        u16* w1h = h1 + zelems;
        u16* w1l = w1h + FEAT * FEAT;
        u16* w2h = w1l + FEAT * FEAT;
        u16* w2l = w2h + FEAT * FEAT;
        u16* wlh = w2l + FEAT * FEAT;
        u16* wll = wlh + CLASSES * FEAT;

        prep_weights<<<64, 256, 0, stream>>>(W1, W2, Wl, w1h, w1l, w2h, w2l, wlh, wll);
        const int blocks = (N_NODES + NPB - 1) / NPB;  // 1563
        gnn_layer1<<<blocks, 256, 0, stream>>>(X, nb, w1h, w1l, h1);
        gnn_layer2_final<<<blocks, 256, 0, stream>>>(h1, nb, w2h, w2l, wlh, wll, out);
    }
}

// Round 2
// 330.124 us; speedup vs baseline: 1.0855x; 1.0855x over previous
//
#include <hip/hip_runtime.h>
#include <cstdint>
#include <cstddef>

typedef unsigned short u16;
typedef __bf16 bf16x8 __attribute__((ext_vector_type(8)));
typedef u16 u16x8 __attribute__((ext_vector_type(8)));
typedef float f32x4 __attribute__((ext_vector_type(4)));

#define N_NODES 100000
#define SAMPLE 25
#define FEAT 128
#define CLASSES 40

__device__ __forceinline__ float bf2f(u16 v) {
    return __uint_as_float(((unsigned)v) << 16);
}
__device__ __forceinline__ u16 f2bf(float f) {
    unsigned u = __float_as_uint(f);
    u += 0x7FFFu + ((u >> 16) & 1u);
    return (u16)(u >> 16);
}
__device__ __forceinline__ void split_bf(float x, u16& hi, u16& lo) {
    hi = f2bf(x);
    lo = f2bf(x - bf2f(hi));
}

__device__ __forceinline__ void split8(const float* ap, bf16x8& ah, bf16x8& al) {
    union { u16x8 u; bf16x8 b; } H, L;
    #pragma unroll
    for (int j = 0; j < 8; ++j) {
        u16 h, lo; split_bf(ap[j], h, lo);
        H.u[j] = h; L.u[j] = lo;
    }
    ah = H.b; al = L.b;
}

__device__ __forceinline__ f32x4 mfma_split(bf16x8 ah, bf16x8 al,
                                            bf16x8 bh, bf16x8 bl, f32x4 acc) {
    acc = __builtin_amdgcn_mfma_f32_16x16x32_bf16(ah, bh, acc, 0, 0, 0);
    acc = __builtin_amdgcn_mfma_f32_16x16x32_bf16(al, bh, acc, 0, 0, 0);
    acc = __builtin_amdgcn_mfma_f32_16x16x32_bf16(ah, bl, acc, 0, 0, 0);
    return acc;
}

// ---------------------------------------------------------------------------
// Static sorting network (Batcher odd-even mergesort, n=32, ascending).
// All indices compile-time (full unroll) -> values stay in VGPRs (rule #20).
// Sort bugs cannot break correctness (mean is permutation-invariant);
// compare-exchange only permutes.
// ---------------------------------------------------------------------------
__device__ __forceinline__ void cex(int& a, int& b) {
    int lo = a < b ? a : b;
    int hi = a < b ? b : a;
    a = lo; b = hi;
}

__device__ __forceinline__ void sort32(int* v) {
    #pragma unroll
    for (int p = 1; p < 32; p <<= 1) {
        #pragma unroll
        for (int k = p; k >= 1; k >>= 1) {
            #pragma unroll
            for (int j = k & (p - 1); j + k < 32; j += 2 * k) {
                #pragma unroll
                for (int i = 0; i < k; ++i) {
                    if (j + i + k < 32) {
                        if (((j + i) / (2 * p)) == ((j + i + k) / (2 * p)))
                            cex(v[j + i], v[j + i + k]);
                    }
                }
            }
        }
    }
}

// ---------------------------------------------------------------------------
// Prep: split fp32 weights into bf16 hi/lo pairs
// ---------------------------------------------------------------------------
__global__ __launch_bounds__(256) void prep_weights(
    const float* __restrict__ W1, const float* __restrict__ W2,
    const float* __restrict__ Wl,
    u16* __restrict__ w1h, u16* __restrict__ w1l,
    u16* __restrict__ w2h, u16* __restrict__ w2l,
    u16* __restrict__ wlh, u16* __restrict__ wll)
{
    const int i = blockIdx.x * 256 + threadIdx.x;
    const int stride = gridDim.x * 256;
    for (int j = i; j < FEAT * FEAT; j += stride) {
        split_bf(W1[j], w1h[j], w1l[j]);
        split_bf(W2[j], w2h[j], w2l[j]);
    }
    for (int j = i; j < CLASSES * FEAT; j += stride) {
        split_bf(Wl[j], wlh[j], wll[j]);
    }
}

// ===========================================================================
// FAST PATH: commuted scheme (Z1 = X@W1^T first, then gather bf16 rows)
// ===========================================================================
#define NPB32 32
#define ZT_STRIDE 136

// K1: Z1 = X @ W1^T  (dense streamed GEMM, bf16 out, LDS-staged stores)
__global__ __launch_bounds__(128, 4) void k1_gemm(
    const float* __restrict__ X,
    const u16* __restrict__ w1h, const u16* __restrict__ w1l,
    u16* __restrict__ Z1)
{
    __shared__ u16 zt[NPB32][ZT_STRIDE];   // 8.7 KB

    const int t = threadIdx.x;
    const int w  = t >> 6;
    const int l  = t & 63;
    const int lr = l & 15;
    const int lq = l >> 4;
    const int blockStart = blockIdx.x * NPB32;
    const float* Xrow = X + (size_t)(blockStart + w * 16 + lr) * FEAT;

    bf16x8 ah[4], al[4];
    #pragma unroll
    for (int k = 0; k < 4; ++k) {
        f32x4 x0 = *(const f32x4*)(Xrow + k * 32 + lq * 8);
        f32x4 x1 = *(const f32x4*)(Xrow + k * 32 + lq * 8 + 4);
        float tmp[8];
        #pragma unroll
        for (int j = 0; j < 4; ++j) { tmp[j] = x0[j]; tmp[4 + j] = x1[j]; }
        split8(tmp, ah[k], al[k]);
    }

    #pragma unroll
    for (int c = 0; c < 8; ++c) {
        f32x4 acc = {0.f, 0.f, 0.f, 0.f};
        #pragma unroll
        for (int k = 0; k < 4; ++k) {
            const size_t off = (size_t)(c * 16 + lr) * FEAT + k * 32 + lq * 8;
            bf16x8 bh = *(const bf16x8*)(w1h + off);
            bf16x8 bl = *(const bf16x8*)(w1l + off);
            acc = mfma_split(ah[k], al[k], bh, bl, acc);
        }
        #pragma unroll
        for (int r = 0; r < 4; ++r)
            zt[w * 16 + lq * 4 + r][c * 16 + lr] = f2bf(acc[r]);  // no relu
    }
    __syncthreads();

    // coalesced 16B stores: 32 rows x 128 u16
    #pragma unroll
    for (int p = 0; p < 4; ++p) {
        const int idx = p * 128 + t;
        const int row = idx >> 4;
        const int col = (idx & 15) * 8;
        *(u16x8*)(Z1 + (size_t)(blockStart + row) * FEAT + col) =
            *(const u16x8*)&zt[row][col];
    }
}

// K2: h1 = relu(mean(Z1[nb])); Z2 = h1 @ W2^T (bf16, LDS-staged stores)
// Neighbor lists sorted ascending in-block -> all co-resident blocks sweep
// Z1 monotonically in near-lockstep -> L2-resident moving band.
__global__ __launch_bounds__(128, 3) void k2_hop(
    const u16* __restrict__ Zin, const int* __restrict__ nb,
    const u16* __restrict__ wh, const u16* __restrict__ wl,
    u16* __restrict__ Zout)
{
    __shared__ int nbs[NPB32 * SAMPLE];
    __shared__ float agg[NPB32][132];      // 16.9 KB, reused as zt later

    const int t = threadIdx.x;
    const int blockStart = blockIdx.x * NPB32;

    for (int i = t; i < NPB32 * SAMPLE; i += 128)
        nbs[i] = nb[blockStart * SAMPLE + i];
    __syncthreads();

    // sort each node's 25 neighbor IDs ascending (locality only; mean is
    // permutation-invariant)
    if (t < NPB32) {
        int v[32];
        #pragma unroll
        for (int s = 0; s < SAMPLE; ++s) v[s] = nbs[t * SAMPLE + s];
        #pragma unroll
        for (int s = SAMPLE; s < 32; ++s) v[s] = 0x7FFFFFFF;
        sort32(v);
        #pragma unroll
        for (int s = 0; s < SAMPLE; ++s) nbs[t * SAMPLE + s] = v[s];
    }
    __syncthreads();

    // gather: burst all 25 loads into registers, then accumulate
    #pragma unroll 1
    for (int it = 0; it < 4; ++it) {
        const int item = t + it * 128;
        const int nl = item >> 4;
        const int fg = item & 15;
        const int* myn = &nbs[nl * SAMPLE];
        u16x8 buf[SAMPLE];
        #pragma unroll
        for (int s = 0; s < SAMPLE; ++s)
            buf[s] = *(const u16x8*)(Zin + ((size_t)myn[s] << 7) + fg * 8);
        float acc[8];
        #pragma unroll
        for (int j = 0; j < 8; ++j) acc[j] = 0.f;
        #pragma unroll
        for (int s = 0; s < SAMPLE; ++s) {
            #pragma unroll
            for (int j = 0; j < 8; ++j) acc[j] += bf2f(buf[s][j]);
        }
        #pragma unroll
        for (int j = 0; j < 8; ++j) {
            float m = acc[j] * (1.0f / SAMPLE);
            agg[nl][fg * 8 + j] = m > 0.f ? m : 0.f;   // relu(mean)
        }
    }
    __syncthreads();

    const int w  = t >> 6;
    const int l  = t & 63;
    const int lr = l & 15;
    const int lq = l >> 4;

    bf16x8 ah[4], al[4];
    #pragma unroll
    for (int k = 0; k < 4; ++k)
        split8(&agg[w * 16 + lr][k * 32 + lq * 8], ah[k], al[k]);
    __syncthreads();                        // A-frags in regs; agg reusable

    u16* zt = (u16*)agg;                    // [NPB32][ZT_STRIDE] u16 view

    #pragma unroll
    for (int c = 0; c < 8; ++c) {
        f32x4 acc = {0.f, 0.f, 0.f, 0.f};
        #pragma unroll
        for (int k = 0; k < 4; ++k) {
            const size_t off = (size_t)(c * 16 + lr) * FEAT + k * 32 + lq * 8;
            bf16x8 bh = *(const bf16x8*)(wh + off);
            bf16x8 bl = *(const bf16x8*)(wl + off);
            acc = mfma_split(ah[k], al[k], bh, bl, acc);
        }
        #pragma unroll
        for (int r = 0; r < 4; ++r)
            zt[(size_t)(w * 16 + lq * 4 + r) * ZT_STRIDE + c * 16 + lr] = f2bf(acc[r]);
    }
    __syncthreads();

    #pragma unroll
    for (int p = 0; p < 4; ++p) {
        const int idx = p * 128 + t;
        const int row = idx >> 4;
        const int col = (idx & 15) * 8;
        *(u16x8*)(Zout + (size_t)(blockStart + row) * FEAT + col) =
            *(const u16x8*)&zt[(size_t)row * ZT_STRIDE + col];
    }
}

// K3: h2 = relu(mean(Z2[nb])); out = h2 @ Wlast^T (fp32, direct stores)
__global__ __launch_bounds__(128, 3) void k3_hop(
    const u16* __restrict__ Zin, const int* __restrict__ nb,
    const u16* __restrict__ wh, const u16* __restrict__ wl,
    float* __restrict__ out)
{
    __shared__ int nbs[NPB32 * SAMPLE];
    __shared__ float agg[NPB32][132];

    const int t = threadIdx.x;
    const int blockStart = blockIdx.x * NPB32;

    for (int i = t; i < NPB32 * SAMPLE; i += 128)
        nbs[i] = nb[blockStart * SAMPLE + i];
    __syncthreads();

    if (t < NPB32) {
        int v[32];
        #pragma unroll
        for (int s = 0; s < SAMPLE; ++s) v[s] = nbs[t * SAMPLE + s];
        #pragma unroll
        for (int s = SAMPLE; s < 32; ++s) v[s] = 0x7FFFFFFF;
        sort32(v);
        #pragma unroll
        for (int s = 0; s < SAMPLE; ++s) nbs[t * SAMPLE + s] = v[s];
    }
    __syncthreads();

    #pragma unroll 1
    for (int it = 0; it < 4; ++it) {
        const int item = t + it * 128;
        const int nl = item >> 4;
        const int fg = item & 15;
        const int* myn = &nbs[nl * SAMPLE];
        u16x8 buf[SAMPLE];
        #pragma unroll
        for (int s = 0; s < SAMPLE; ++s)
            buf[s] = *(const u16x8*)(Zin + ((size_t)myn[s] << 7) + fg * 8);
        float acc[8];
        #pragma unroll
        for (int j = 0; j < 8; ++j) acc[j] = 0.f;
        #pragma unroll
        for (int s = 0; s < SAMPLE; ++s) {
            #pragma unroll
            for (int j = 0; j < 8; ++j) acc[j] += bf2f(buf[s][j]);
        }
        #pragma unroll
        for (int j = 0; j < 8; ++j) {
            float m = acc[j] * (1.0f / SAMPLE);
            agg[nl][fg * 8 + j] = m > 0.f ? m : 0.f;   // relu(mean)
        }
    }
    __syncthreads();

    const int w  = t >> 6;
    const int l  = t & 63;
    const int lr = l & 15;
    const int lq = l >> 4;

    bf16x8 ah[4], al[4];
    #pragma unroll
    for (int k = 0; k < 4; ++k)
        split8(&agg[w * 16 + lr][k * 32 + lq * 8], ah[k], al[k]);

    #pragma unroll
    for (int c = 0; c < 3; ++c) {
        const int o = c * 16 + lr;
        f32x4 acc = {0.f, 0.f, 0.f, 0.f};
        #pragma unroll
        for (int k = 0; k < 4; ++k) {
            bf16x8 bh, bl;
            if (o < CLASSES) {
                const size_t off = (size_t)o * FEAT + k * 32 + lq * 8;
                bh = *(const bf16x8*)(wh + off);
                bl = *(const bf16x8*)(wl + off);
            } else {
                #pragma unroll
                for (int j = 0; j < 8; ++j) { bh[j] = (__bf16)0.f; bl[j] = (__bf16)0.f; }
            }
            acc = mfma_split(ah[k], al[k], bh, bl, acc);
        }
        if (o < CLASSES) {
            #pragma unroll
            for (int r = 0; r < 4; ++r) {
                const int node = blockStart + w * 16 + lq * 4 + r;
                out[(size_t)node * CLASSES + o] = acc[r];
            }
        }
    }
}

// ===========================================================================
// FALLBACK PATH (proven R2 kernels, ws >= 25.9 MB only)
// ===========================================================================
#define NPB 64
#define AGG_STRIDE 136

__global__ __launch_bounds__(256) void gnn_layer1(
    const float* __restrict__ X, const int* __restrict__ nb,
    const u16* __restrict__ w1h, const u16* __restrict__ w1l,
    u16* __restrict__ h1)
{
    __shared__ int nbs[NPB * SAMPLE];
    __shared__ u16 agg_h[NPB][AGG_STRIDE];
    __shared__ u16 agg_l[NPB][AGG_STRIDE];

    const int t = threadIdx.x;
    const int blockStart = blockIdx.x * NPB;

    for (int i = t; i < NPB * SAMPLE; i += 256) {
        int gi = blockStart * SAMPLE + i;
        if (gi >= N_NODES * SAMPLE) gi = N_NODES * SAMPLE - 1;
        nbs[i] = nb[gi];
    }
    __syncthreads();

    for (int item = t; item < NPB * 16; item += 256) {
        const int nl = item >> 4;
        const int fg = item & 15;
        float acc[8];
        #pragma unroll
        for (int j = 0; j < 8; ++j) acc[j] = 0.f;
        const int* myn = &nbs[nl * SAMPLE];
        for (int s = 0; s < SAMPLE; ++s) {
            const float4* p = (const float4*)(X + (size_t)myn[s] * FEAT + fg * 8);
            float4 a = p[0], b = p[1];
            acc[0] += a.x; acc[1] += a.y; acc[2] += a.z; acc[3] += a.w;
            acc[4] += b.x; acc[5] += b.y; acc[6] += b.z; acc[7] += b.w;
        }
        u16x8 oh, ol;
        #pragma unroll
        for (int j = 0; j < 8; ++j) {
            float m = acc[j] * (1.0f / SAMPLE);
            u16 h, lo; split_bf(m, h, lo);
            oh[j] = h; ol[j] = lo;
        }
        *(u16x8*)&agg_h[nl][fg * 8] = oh;
        *(u16x8*)&agg_l[nl][fg * 8] = ol;
    }
    __syncthreads();

    const int w  = t >> 6;
    const int l  = t & 63;
    const int lr = l & 15;
    const int lq = l >> 4;

    bf16x8 ah[4], al[4];
    #pragma unroll
    for (int k = 0; k < 4; ++k) {
        ah[k] = *(const bf16x8*)&agg_h[w * 16 + lr][k * 32 + lq * 8];
        al[k] = *(const bf16x8*)&agg_l[w * 16 + lr][k * 32 + lq * 8];
    }

    #pragma unroll
    for (int c = 0; c < 8; ++c) {
        f32x4 acc = {0.f, 0.f, 0.f, 0.f};
        #pragma unroll
        for (int k = 0; k < 4; ++k) {
            const size_t off = (size_t)(c * 16 + lr) * FEAT + k * 32 + lq * 8;
            bf16x8 bh = *(const bf16x8*)(w1h + off);
            bf16x8 bl = *(const bf16x8*)(w1l + off);
            acc = mfma_split(ah[k], al[k], bh, bl, acc);
        }
        #pragma unroll
        for (int r = 0; r < 4; ++r) {
            int node = blockStart + w * 16 + lq * 4 + r;
            if (node < N_NODES) {
                float v = acc[r] > 0.f ? acc[r] : 0.f;
                h1[(size_t)node * FEAT + c * 16 + lr] = f2bf(v);
            }
        }
    }
}

__global__ __launch_bounds__(256) void gnn_layer2_final(
    const u16* __restrict__ h1, const int* __restrict__ nb,
    const u16* __restrict__ w2h, const u16* __restrict__ w2l,
    const u16* __restrict__ wlh, const u16* __restrict__ wll,
    float* __restrict__ out)
{
    __shared__ int nbs[NPB * SAMPLE];
    __shared__ u16 agg_h[NPB][AGG_STRIDE];
    __shared__ u16 agg_l[NPB][AGG_STRIDE];

    const int t = threadIdx.x;
    const int blockStart = blockIdx.x * NPB;

    for (int i = t; i < NPB * SAMPLE; i += 256) {
        int gi = blockStart * SAMPLE + i;
        if (gi >= N_NODES * SAMPLE) gi = N_NODES * SAMPLE - 1;
        nbs[i] = nb[gi];
    }
    __syncthreads();

    for (int item = t; item < NPB * 16; item += 256) {
        const int nl = item >> 4;
        const int fg = item & 15;
        float acc[8];
        #pragma unroll
        for (int j = 0; j < 8; ++j) acc[j] = 0.f;
        const int* myn = &nbs[nl * SAMPLE];
        for (int s = 0; s < SAMPLE; ++s) {
            u16x8 v = *(const u16x8*)(h1 + (size_t)myn[s] * FEAT + fg * 8);
            #pragma unroll
            for (int j = 0; j < 8; ++j) acc[j] += bf2f(v[j]);
        }
        u16x8 oh, ol;
        #pragma unroll
        for (int j = 0; j < 8; ++j) {
            float m = acc[j] * (1.0f / SAMPLE);
            u16 h, lo; split_bf(m, h, lo);
            oh[j] = h; ol[j] = lo;
        }
        *(u16x8*)&agg_h[nl][fg * 8] = oh;
        *(u16x8*)&agg_l[nl][fg * 8] = ol;
    }
    __syncthreads();

    const int w  = t >> 6;
    const int l  = t & 63;
    const int lr = l & 15;
    const int lq = l >> 4;

    f32x4 hacc[8];
    {
        bf16x8 ah[4], al[4];
        #pragma unroll
        for (int k = 0; k < 4; ++k) {
            ah[k] = *(const bf16x8*)&agg_h[w * 16 + lr][k * 32 + lq * 8];
            al[k] = *(const bf16x8*)&agg_l[w * 16 + lr][k * 32 + lq * 8];
        }
        #pragma unroll
        for (int c = 0; c < 8; ++c) {
            f32x4 acc = {0.f, 0.f, 0.f, 0.f};
            #pragma unroll
            for (int k = 0; k < 4; ++k) {
                const size_t off = (size_t)(c * 16 + lr) * FEAT + k * 32 + lq * 8;
                bf16x8 bh = *(const bf16x8*)(w2h + off);
                bf16x8 bl = *(const bf16x8*)(w2l + off);
                acc = mfma_split(ah[k], al[k], bh, bl, acc);
            }
            hacc[c] = acc;
        }
    }
    __syncthreads();

    #pragma unroll
    for (int c = 0; c < 8; ++c) {
        #pragma unroll
        for (int r = 0; r < 4; ++r) {
            float v = hacc[c][r] > 0.f ? hacc[c][r] : 0.f;
            u16 h, l2; split_bf(v, h, l2);
            agg_h[w * 16 + lq * 4 + r][c * 16 + lr] = h;
            agg_l[w * 16 + lq * 4 + r][c * 16 + lr] = l2;
        }
    }
    __syncthreads();

    {
        bf16x8 ah[4], al[4];
        #pragma unroll
        for (int k = 0; k < 4; ++k) {
            ah[k] = *(const bf16x8*)&agg_h[w * 16 + lr][k * 32 + lq * 8];
            al[k] = *(const bf16x8*)&agg_l[w * 16 + lr][k * 32 + lq * 8];
        }
        #pragma unroll
        for (int c = 0; c < 3; ++c) {
            const int o = c * 16 + lr;
            f32x4 acc = {0.f, 0.f, 0.f, 0.f};
            #pragma unroll
            for (int k = 0; k < 4; ++k) {
                bf16x8 bh, bl;
                if (o < CLASSES) {
                    const size_t off = (size_t)o * FEAT + k * 32 + lq * 8;
                    bh = *(const bf16x8*)(wlh + off);
                    bl = *(const bf16x8*)(wll + off);
                } else {
                    #pragma unroll
                    for (int j = 0; j < 8; ++j) { bh[j] = (__bf16)0.f; bl[j] = (__bf16)0.f; }
                }
                acc = mfma_split(ah[k], al[k], bh, bl, acc);
            }
            if (o < CLASSES) {
                #pragma unroll
                for (int r = 0; r < 4; ++r) {
                    int node = blockStart + w * 16 + lq * 4 + r;
                    if (node < N_NODES) {
                        out[(size_t)node * CLASSES + o] = acc[r];
                    }
                }
            }
        }
    }
}

extern "C" void kernel_launch(void* const* d_in, const int* in_sizes, int n_in,
                              void* d_out, int out_size, void* d_ws, size_t ws_size,
                              hipStream_t stream) {
    const float* X  = (const float*)d_in[0];
    const int*   nb = (const int*)d_in[1];
    const float* W1 = (const float*)d_in[2];
    const float* W2 = (const float*)d_in[3];
    const float* Wl = (const float*)d_in[4];
    float* out = (float*)d_out;

    const size_t zelems = (size_t)N_NODES * FEAT;                 // 12.8M
    const size_t welems = 4 * (size_t)FEAT * FEAT + 2 * (size_t)CLASSES * FEAT;
    const size_t need_fast = (2 * zelems + welems) * sizeof(u16); // ~51.4 MB

    if (ws_size >= need_fast) {
        u16* Z1  = (u16*)d_ws;
        u16* Z2  = Z1 + zelems;
        u16* w1h = Z2 + zelems;
        u16* w1l = w1h + FEAT * FEAT;
        u16* w2h = w1l + FEAT * FEAT;
        u16* w2l = w2h + FEAT * FEAT;
        u16* wlh = w2l + FEAT * FEAT;
        u16* wll = wlh + CLASSES * FEAT;

        prep_weights<<<64, 256, 0, stream>>>(W1, W2, Wl, w1h, w1l, w2h, w2l, wlh, wll);
        const int blocks = N_NODES / NPB32;  // 3125, exact
        k1_gemm<<<blocks, 128, 0, stream>>>(X, w1h, w1l, Z1);
        k2_hop<<<blocks, 128, 0, stream>>>(Z1, nb, w2h, w2l, Z2);
        k3_hop<<<blocks, 128, 0, stream>>>(Z2, nb, wlh, wll, out);
    } else {
        u16* h1  = (u16*)d_ws;
        u16* w1h = h1 + zelems;
        u16* w1l = w1h + FEAT * FEAT;
        u16* w2h = w1l + FEAT * FEAT;
        u16* w2l = w2h + FEAT * FEAT;
        u16* wlh = w2l + FEAT * FEAT;
        u16* wll = wlh + CLASSES * FEAT;

        prep_weights<<<64, 256, 0, stream>>>(W1, W2, Wl, w1h, w1l, w2h, w2l, wlh, wll);
        const int blocks = (N_NODES + NPB - 1) / NPB;  // 1563
        gnn_layer1<<<blocks, 256, 0, stream>>>(X, nb, w1h, w1l, h1);
        gnn_layer2_final<<<blocks, 256, 0, stream>>>(h1, nb, w2h, w2l, wlh, wll, out);
    }
}